// Round 1
// baseline (162.709 us; speedup 1.0000x reference)
//
#include <hip/hip_runtime.h>
#include <stdint.h>
#include <stddef.h>

#define C_TOTAL     256
#define CPG         4                    // channels per block (one wave each)
#define NGROUPS     (C_TOTAL / CPG)      // 64
#define NBINS       49
#define NSAMP       196                  // 14 x 14 sample grid
#define MAX_CELLS   1664                 // proven bound ~1600 for any legal roi/level
#define TILE_STRIDE (MAX_CELLS + 64)     // slack for clamped last staging chunk

__global__ __launch_bounds__(256, 4)
void roi_align_fused(const float* __restrict__ f0,
                     const float* __restrict__ f1,
                     const float* __restrict__ f2,
                     const float* __restrict__ f3,
                     const float* __restrict__ rois,
                     float* __restrict__ out)
{
    __shared__ float  s_tile[CPG * TILE_STRIDE];
    __shared__ float4 s_w4[NSAMP];   // 4 bilinear weights (x 0.25 mean, 0 if invalid)
    __shared__ int4   s_c4[NSAMP];   // 4 tap cell indices into the tile

    const int k    = blockIdx.y;     // roi
    const int g    = blockIdx.x;     // channel group
    const int tid  = threadIdx.x;
    const int wv   = tid >> 6;       // wave id = local channel
    const int lane = tid & 63;

    // ---------------- ROI params (uniform; every thread computes) --------------
    const float bf  = rois[k * 5 + 0];
    const float rx1 = rois[k * 5 + 1];
    const float ry1 = rois[k * 5 + 2];
    const float rx2 = rois[k * 5 + 3];
    const float ry2 = rois[k * 5 + 4];
    const int   b   = (int)bf;

    const float scale = sqrtf((rx2 - rx1 + 1.0f) * (ry2 - ry1 + 1.0f));
    int lvl = (int)floorf(log2f(scale / 56.0f + 1e-6f));
    lvl = lvl < 0 ? 0 : (lvl > 3 ? 3 : lvl);

    const float* feat; int H, W;
    if      (lvl == 0) { feat = f0; H = 200; W = 336; }
    else if (lvl == 1) { feat = f1; H = 100; W = 168; }
    else if (lvl == 2) { feat = f2; H =  50; W =  84; }
    else               { feat = f3; H =  25; W =  42; }

    const float ss  = 1.0f / (float)(4 << lvl);
    const float x1s = rx1 * ss, y1s = ry1 * ss;
    const float x2s = rx2 * ss, y2s = ry2 * ss;
    const float roi_w = fmaxf(x2s - x1s, 1.0f);
    const float roi_h = fmaxf(y2s - y1s, 1.0f);
    const float bw = roi_w * (1.0f / 7.0f);
    const float bh = roi_h * (1.0f / 7.0f);

    const float Hm1 = (float)(H - 1), Wm1 = (float)(W - 1);
    // sample extremes: first sample offset 0.25*bin, last 6.75*bin
    const int ty0 = (int)floorf(fminf(fmaxf(y1s + 0.25f * bh, 0.0f), Hm1));
    const int tx0 = (int)floorf(fminf(fmaxf(x1s + 0.25f * bw, 0.0f), Wm1));
    const int ty1 = min((int)floorf(fminf(fmaxf(y1s + 6.75f * bh, 0.0f), Hm1)) + 1, H - 1);
    const int tx1 = min((int)floorf(fminf(fmaxf(x1s + 6.75f * bw, 0.0f), Wm1)) + 1, W - 1);
    const int fh = ty1 - ty0 + 1;
    const int fw = tx1 - tx0 + 1;
    int cells = fh * fw;
    cells = cells > MAX_CELLS ? MAX_CELLS : cells;   // safety net; mathematically unreachable

    // ---------------- stage footprint: one wave per channel, async -------------
    {
        const int c = g * CPG + wv;
        const float* src = feat + ((size_t)(b * C_TOTAL + c) * (size_t)H + (size_t)ty0) * (size_t)W + tx0;
        float* dst = s_tile + wv * TILE_STRIDE;
        for (int base = 0; base < cells; base += 64) {
            int cell = base + lane;
            cell = cell < cells ? cell : (cells - 1);        // clamp last chunk (dups land in slack)
            const int fy = (int)((unsigned)cell / (unsigned)fw);
            const int fx = cell - fy * fw;
            __builtin_amdgcn_global_load_lds(
                (const __attribute__((address_space(1))) uint32_t*)(src + (size_t)fy * W + fx),
                (__attribute__((address_space(3))) uint32_t*)(dst + base),
                4, 0, 0);
        }
    }

    // ---------------- sample descriptors (while loads are in flight) -----------
    if (tid < NSAMP) {
        const int iy = tid / 14;
        const int ix = tid - iy * 14;
        const float yy = y1s + ((float)iy * 0.5f + 0.25f) * bh;
        const float xx = x1s + ((float)ix * 0.5f + 0.25f) * bw;
        const bool valid = (yy > -1.0f) && (yy < (float)H) && (xx > -1.0f) && (xx < (float)W);
        const float yc  = fminf(fmaxf(yy, 0.0f), Hm1);
        const float xc  = fminf(fmaxf(xx, 0.0f), Wm1);
        const float y0f = floorf(yc);
        const float x0f = floorf(xc);
        const float ly = yc - y0f, lx = xc - x0f;
        const float hy = 1.0f - ly, hx = 1.0f - lx;
        const int y0  = (int)y0f, x0 = (int)x0f;
        const int y1i = min(y0 + 1, H - 1);
        const int x1i = min(x0 + 1, W - 1);
        const int ry0 = y0  - ty0, ry1b = y1i - ty0;
        const int rx0 = x0  - tx0, rx1b = x1i - tx0;
        const float v = valid ? 0.25f : 0.0f;       // fold the 4-sample mean in here
        s_w4[tid] = make_float4(hy * hx * v, hy * lx * v, ly * hx * v, ly * lx * v);
        s_c4[tid] = make_int4(ry0 * fw + rx0, ry0 * fw + rx1b,
                              ry1b * fw + rx0, ry1b * fw + rx1b);
    }

    asm volatile("s_waitcnt vmcnt(0)" ::: "memory");
    __syncthreads();

    // ---------------- bilinear from LDS, one bin per lane ----------------------
    if (lane < NBINS) {
        const float* t = s_tile + wv * TILE_STRIDE;
        const int oy = lane / 7;
        const int ox = lane - oy * 7;
        const int sbase = oy * 28 + ox * 2;   // iy = 2*oy, ix = 2*ox  -> s = iy*14 + ix
        float acc = 0.0f;
#pragma unroll
        for (int sy = 0; sy < 2; ++sy) {
#pragma unroll
            for (int sx = 0; sx < 2; ++sx) {
                const int s = sbase + sy * 14 + sx;
                const float4 w = s_w4[s];
                const int4   cc = s_c4[s];
                acc += w.x * t[cc.x] + w.y * t[cc.y]
                     + w.z * t[cc.z] + w.w * t[cc.w];
            }
        }
        const int c = g * CPG + wv;
        out[((size_t)k * C_TOTAL + c) * NBINS + lane] = acc;
    }
}

extern "C" void kernel_launch(void* const* d_in, const int* in_sizes, int n_in,
                              void* d_out, int out_size, void* d_ws, size_t ws_size,
                              hipStream_t stream) {
    const float* f0   = (const float*)d_in[0];
    const float* f1   = (const float*)d_in[1];
    const float* f2   = (const float*)d_in[2];
    const float* f3   = (const float*)d_in[3];
    const float* rois = (const float*)d_in[4];
    float* out = (float*)d_out;

    const int K = in_sizes[4] / 5;
    dim3 grid(NGROUPS, K, 1);
    roi_align_fused<<<grid, 256, 0, stream>>>(f0, f1, f2, f3, rois, out);
}

// Round 2
// 147.143 us; speedup vs baseline: 1.1058x; 1.1058x over previous
//
#include <hip/hip_runtime.h>
#include <stdint.h>
#include <stddef.h>

#define C_TOTAL     256
#define CPG         4                    // channels per block (one wave each)
#define NGROUPS     (C_TOTAL / CPG)      // 64
#define NBINS       49
#define TILE_D      1920                 // dwords per channel tile (proven bound ~<=1900 padded)
#define CHUNK16_MAX (TILE_D / 4)         // 480 dwordx4 chunks

__global__ __launch_bounds__(256, 5)
void roi_align_fused(const float* __restrict__ f0,
                     const float* __restrict__ f1,
                     const float* __restrict__ f2,
                     const float* __restrict__ f3,
                     const float* __restrict__ rois,
                     float* __restrict__ out)
{
    __shared__ __align__(16) float s_tile[CPG * TILE_D];   // 30720 B -> 5 blocks/CU

    const int k    = blockIdx.y;     // roi
    const int g    = blockIdx.x;     // channel group
    const int tid  = threadIdx.x;
    const int wv   = tid >> 6;       // wave id = local channel
    const int lane = tid & 63;

    // ---------------- ROI params (uniform; every thread computes) --------------
    const float bf  = rois[k * 5 + 0];
    const float rx1 = rois[k * 5 + 1];
    const float ry1 = rois[k * 5 + 2];
    const float rx2 = rois[k * 5 + 3];
    const float ry2 = rois[k * 5 + 4];
    const int   b   = (int)bf;

    const float scale = sqrtf((rx2 - rx1 + 1.0f) * (ry2 - ry1 + 1.0f));
    int lvl = (int)floorf(log2f(scale / 56.0f + 1e-6f));
    lvl = lvl < 0 ? 0 : (lvl > 3 ? 3 : lvl);

    const float* feat; int H, W;
    if      (lvl == 0) { feat = f0; H = 200; W = 336; }
    else if (lvl == 1) { feat = f1; H = 100; W = 168; }
    else if (lvl == 2) { feat = f2; H =  50; W =  84; }
    else               { feat = f3; H =  25; W =  42; }

    const float ss  = 1.0f / (float)(4 << lvl);
    const float x1s = rx1 * ss, y1s = ry1 * ss;
    const float x2s = rx2 * ss, y2s = ry2 * ss;
    const float roi_w = fmaxf(x2s - x1s, 1.0f);
    const float roi_h = fmaxf(y2s - y1s, 1.0f);
    const float bw = roi_w * (1.0f / 7.0f);
    const float bh = roi_h * (1.0f / 7.0f);

    const float Hm1 = (float)(H - 1), Wm1 = (float)(W - 1);
    // footprint rows/cols from first (0.25*bin) and last (6.75*bin) sample
    const int ty0 = (int)floorf(fminf(fmaxf(y1s + 0.25f * bh, 0.0f), Hm1));
    const int tx0 = (int)floorf(fminf(fmaxf(x1s + 0.25f * bw, 0.0f), Wm1));
    const int ty1 = min((int)floorf(fminf(fmaxf(y1s + 6.75f * bh, 0.0f), Hm1)) + 1, H - 1);
    const int tx1 = min((int)floorf(fminf(fmaxf(x1s + 6.75f * bw, 0.0f), Wm1)) + 1, W - 1);
    const int fh = ty1 - ty0 + 1;
    const int fw = tx1 - tx0 + 1;

    // ---------------- staging geometry --------------------------------------
    // Path A (levels 0-2, W%4==0): dwordx4 chunks, rows padded to 4*cpr dwords,
    // left edge rb aligned to 4 dwords -> every chunk 16B aligned.
    // Path B (level 3 or oversized padded tile): width-4 flat-cell staging.
    int cpr = (fw + (tx0 & 3) + 3) >> 2;
    if (cpr > (W >> 2)) cpr = W >> 2;                 // safety (unreachable)
    const bool use16 = (lvl < 3) && (fh * cpr <= CHUNK16_MAX);

    int rb, rowStride, chunks;
    if (use16) {
        rb = tx0 & ~3;
        if (rb + 4 * cpr > W) rb = W - 4 * cpr;       // stays 4-aligned (W%4==0)
        rowStride = 4 * cpr;
        chunks = fh * cpr;
    } else {
        rb = tx0;
        rowStride = fw;
        chunks = fh * fw;
        if (chunks > TILE_D) chunks = TILE_D;         // safety (unreachable)
    }
    const uint32_t d = use16 ? (uint32_t)cpr : (uint32_t)fw;
    const uint32_t M = (1u << 22) / d + 1u;           // exact div for idx<1920, d<=336
    const int dW = W - rowStride;

    // ---------------- stage footprint: one wave per channel, async -------------
    {
        const int c = g * CPG + wv;
        const float* src = feat + ((size_t)(b * C_TOTAL + c) * (size_t)H + (size_t)ty0) * (size_t)W + rb;
        float* dst = s_tile + wv * TILE_D;
        if (use16) {
            for (int start = 0; start < chunks; start += 64) {
                int s = (start + 64 > chunks) ? max(chunks - 64, 0) : start;  // overlap tail
                int idx = s + lane;
                if (idx >= chunks) idx = chunks - 1;          // only when chunks<64
                const int fy = (int)(((uint32_t)idx * M) >> 22);
                const int off = (idx << 2) + fy * dW;
                __builtin_amdgcn_global_load_lds(
                    (const __attribute__((address_space(1))) uint32_t*)(src + off),
                    (__attribute__((address_space(3))) uint32_t*)(dst + (s << 2)),
                    16, 0, 0);
            }
        } else {
            for (int start = 0; start < chunks; start += 64) {
                int s = (start + 64 > chunks) ? max(chunks - 64, 0) : start;
                int idx = s + lane;
                if (idx >= chunks) idx = chunks - 1;
                const int fy = (int)(((uint32_t)idx * M) >> 22);
                const int off = idx + fy * dW;
                __builtin_amdgcn_global_load_lds(
                    (const __attribute__((address_space(1))) uint32_t*)(src + off),
                    (__attribute__((address_space(3))) uint32_t*)(dst + s),
                    4, 0, 0);
            }
        }
    }

    asm volatile("s_waitcnt vmcnt(0)" ::: "memory");
    __syncthreads();

    // ---------------- bilinear from LDS, one bin per lane ----------------------
    if (lane < NBINS) {
        const float* t = s_tile + wv * TILE_D;
        const int oy = lane / 7;
        const int ox = lane - oy * 7;
        const float Hf = (float)H, Wf = (float)W;
        float acc = 0.0f;
#pragma unroll
        for (int sy = 0; sy < 2; ++sy) {
#pragma unroll
            for (int sx = 0; sx < 2; ++sx) {
                const float yy = y1s + ((float)oy + 0.25f + 0.5f * (float)sy) * bh;
                const float xx = x1s + ((float)ox + 0.25f + 0.5f * (float)sx) * bw;
                const bool valid = (yy > -1.0f) && (yy < Hf) && (xx > -1.0f) && (xx < Wf);
                const float yc  = fminf(fmaxf(yy, 0.0f), Hm1);
                const float xc  = fminf(fmaxf(xx, 0.0f), Wm1);
                const float y0f = floorf(yc);
                const float x0f = floorf(xc);
                const float ly = yc - y0f, lx = xc - x0f;
                const float hy = 1.0f - ly, hx = 1.0f - lx;
                const int y0  = (int)y0f, x0 = (int)x0f;
                const int y1i = min(y0 + 1, H - 1);
                const int x1i = min(x0 + 1, W - 1);
                const int r0 = (y0  - ty0) * rowStride - rb;
                const int r1 = (y1i - ty0) * rowStride - rb;
                const float v = valid ? 0.25f : 0.0f;     // fold 4-sample mean
                acc += (hy * hx * v) * t[r0 + x0]
                     + (hy * lx * v) * t[r0 + x1i]
                     + (ly * hx * v) * t[r1 + x0]
                     + (ly * lx * v) * t[r1 + x1i];
            }
        }
        const int c = g * CPG + wv;
        out[((size_t)k * C_TOTAL + c) * NBINS + lane] = acc;
    }
}

extern "C" void kernel_launch(void* const* d_in, const int* in_sizes, int n_in,
                              void* d_out, int out_size, void* d_ws, size_t ws_size,
                              hipStream_t stream) {
    const float* f0   = (const float*)d_in[0];
    const float* f1   = (const float*)d_in[1];
    const float* f2   = (const float*)d_in[2];
    const float* f3   = (const float*)d_in[3];
    const float* rois = (const float*)d_in[4];
    float* out = (float*)d_out;

    const int K = in_sizes[4] / 5;
    dim3 grid(NGROUPS, K, 1);
    roi_align_fused<<<grid, 256, 0, stream>>>(f0, f1, f2, f3, rois, out);
}

// Round 3
// 146.116 us; speedup vs baseline: 1.1136x; 1.0070x over previous
//
#include <hip/hip_runtime.h>
#include <stdint.h>
#include <stddef.h>

#define C_TOTAL   256
#define CPG       4                    // channels per block (one wave each)
#define NGROUPS   (C_TOTAL / CPG)      // 64
#define NBINS     49
#define NSAMP     196                  // 14 x 14 sample grid
#define TILE_D    1280                 // dwords per channel tile (bound ~1020 + margin)
#define SD_STRIDE 16                   // ints per roi scalar descriptor
#define BLOB_DW   (NSAMP * 8)          // 1568 dwords: 196 float4 w + 196 int4 c
#define DESC_CHUNKS (BLOB_DW / 4)      // 392 dwordx4 chunks
#define WCHUNK    (DESC_CHUNKS / 4)    // 98 chunks per wave

// ---------------------------------------------------------------------------
// Pre-kernel: one block per roi. Computes scalar staging geometry + all 196
// sample descriptors (weights folded with 0.25 mean & validity; tap indices
// relative to the staged tile).
// ---------------------------------------------------------------------------
__global__ __launch_bounds__(256)
void roi_desc_kernel(const float* __restrict__ rois, int* __restrict__ ws_i,
                     int blobBase /* dword offset of blob region */)
{
    const int k   = blockIdx.x;
    const int tid = threadIdx.x;

    const float bf  = rois[k * 5 + 0];
    const float rx1 = rois[k * 5 + 1];
    const float ry1 = rois[k * 5 + 2];
    const float rx2 = rois[k * 5 + 3];
    const float ry2 = rois[k * 5 + 4];
    const int   b   = (int)bf;

    const float scale = sqrtf((rx2 - rx1 + 1.0f) * (ry2 - ry1 + 1.0f));
    int lvl = (int)floorf(log2f(scale / 56.0f + 1e-6f));
    lvl = lvl < 0 ? 0 : (lvl > 3 ? 3 : lvl);

    int H, W;
    if      (lvl == 0) { H = 200; W = 336; }
    else if (lvl == 1) { H = 100; W = 168; }
    else if (lvl == 2) { H =  50; W =  84; }
    else               { H =  25; W =  42; }

    const float ss  = 1.0f / (float)(4 << lvl);
    const float x1s = rx1 * ss, y1s = ry1 * ss;
    const float x2s = rx2 * ss, y2s = ry2 * ss;
    const float roi_w = fmaxf(x2s - x1s, 1.0f);
    const float roi_h = fmaxf(y2s - y1s, 1.0f);
    const float bw = roi_w * (1.0f / 7.0f);
    const float bh = roi_h * (1.0f / 7.0f);

    const float Hm1 = (float)(H - 1), Wm1 = (float)(W - 1);
    const int ty0 = (int)floorf(fminf(fmaxf(y1s + 0.25f * bh, 0.0f), Hm1));
    const int tx0 = (int)floorf(fminf(fmaxf(x1s + 0.25f * bw, 0.0f), Wm1));
    const int ty1 = min((int)floorf(fminf(fmaxf(y1s + 6.75f * bh, 0.0f), Hm1)) + 1, H - 1);
    const int tx1 = min((int)floorf(fminf(fmaxf(x1s + 6.75f * bw, 0.0f), Wm1)) + 1, W - 1);
    const int fh = ty1 - ty0 + 1;
    const int fw = tx1 - tx0 + 1;

    int cpr = (fw + (tx0 & 3) + 3) >> 2;
    if (cpr > (W >> 2)) cpr = W >> 2;
    const bool use16 = (lvl < 3) && (fh * cpr <= TILE_D / 4);

    int rb, rowStride, chunks;
    if (use16) {
        rb = tx0 & ~3;
        if (rb + 4 * cpr > W) rb = W - 4 * cpr;   // stays 4-aligned (W%4==0 for lvl<3)
        rowStride = 4 * cpr;
        chunks = fh * cpr;                        // dwordx4 units
        if (chunks > TILE_D / 4) chunks = TILE_D / 4;   // unreachable safety
    } else {
        rb = tx0;
        rowStride = fw;
        chunks = fh * fw;                         // dword units
        if (chunks > TILE_D) chunks = TILE_D;     // unreachable safety
    }
    const uint32_t d = use16 ? (uint32_t)cpr : (uint32_t)fw;
    const uint32_t M = (1u << 22) / d + 1u;       // exact for idx<1920, d<=336
    const int dW = W - rowStride;

    if (tid == 0) {
        int* sd = ws_i + k * SD_STRIDE;
        sd[0] = lvl;
        sd[1] = use16 ? 1 : 0;
        sd[2] = b * C_TOTAL * H * W + ty0 * W + rb;   // channel-0 dword offset
        sd[3] = chunks;
        sd[4] = (int)M;
        sd[5] = dW;
        sd[6] = H * W;                                // channel stride
    }

    if (tid < NSAMP) {
        const int iy = tid / 14;
        const int ix = tid - iy * 14;
        const float yy = y1s + ((float)iy * 0.5f + 0.25f) * bh;
        const float xx = x1s + ((float)ix * 0.5f + 0.25f) * bw;
        const bool valid = (yy > -1.0f) && (yy < (float)H) && (xx > -1.0f) && (xx < (float)W);
        const float yc  = fminf(fmaxf(yy, 0.0f), Hm1);
        const float xc  = fminf(fmaxf(xx, 0.0f), Wm1);
        const float y0f = floorf(yc);
        const float x0f = floorf(xc);
        const float ly = yc - y0f, lx = xc - x0f;
        const float hy = 1.0f - ly, hx = 1.0f - lx;
        const int y0  = (int)y0f, x0 = (int)x0f;
        const int y1i = min(y0 + 1, H - 1);
        const int x1i = min(x0 + 1, W - 1);
        const int r0 = (y0  - ty0) * rowStride - rb;
        const int r1 = (y1i - ty0) * rowStride - rb;
        const float v = valid ? 0.25f : 0.0f;         // fold 4-sample mean
        float4* w4 = (float4*)(ws_i + blobBase + k * BLOB_DW);
        int4*   c4 = (int4*)  (ws_i + blobBase + k * BLOB_DW + 4 * NSAMP);
        w4[tid] = make_float4(hy * hx * v, hy * lx * v, ly * hx * v, ly * lx * v);
        c4[tid] = make_int4(r0 + x0, r0 + x1i, r1 + x0, r1 + x1i);
    }
}

// ---------------------------------------------------------------------------
// Main kernel: zero roi math. Stage tile + descriptor blob into LDS, gather.
// ---------------------------------------------------------------------------
__global__ __launch_bounds__(256, 6)
void roi_align_main(const float* __restrict__ f0,
                    const float* __restrict__ f1,
                    const float* __restrict__ f2,
                    const float* __restrict__ f3,
                    const int* __restrict__ ws_i,
                    float* __restrict__ out,
                    int blobBase)
{
    __shared__ __align__(16) float s_tile[CPG * TILE_D];   // 20480 B
    __shared__ __align__(16) float s_desc[BLOB_DW];        //  6272 B -> 6 blocks/CU

    const int k    = blockIdx.y;
    const int g    = blockIdx.x;
    const int tid  = threadIdx.x;
    const int wv   = tid >> 6;
    const int lane = tid & 63;

    const int* sd = ws_i + k * SD_STRIDE;
    const int lvl     = sd[0];
    const int use16   = sd[1];
    const int srcBase = sd[2];
    const int chunks  = sd[3];
    const uint32_t M  = (uint32_t)sd[4];
    const int dW      = sd[5];
    const int HW      = sd[6];

    const float* feat = (lvl == 0) ? f0 : (lvl == 1) ? f1 : (lvl == 2) ? f2 : f3;

    // ---- tile staging: one wave per channel, async ----
    {
        const int c = g * CPG + wv;
        const float* src = feat + srcBase + (size_t)c * (size_t)HW;
        float* dst = s_tile + wv * TILE_D;
        if (use16) {
            for (int start = 0; start < chunks; start += 64) {
                int s = (start + 64 > chunks) ? max(chunks - 64, 0) : start;  // overlap tail
                int idx = s + lane;
                if (idx >= chunks) idx = chunks - 1;     // only when chunks<64
                const int fy  = (int)(((uint32_t)idx * M) >> 22);
                const int off = (idx << 2) + fy * dW;
                __builtin_amdgcn_global_load_lds(
                    (const __attribute__((address_space(1))) uint32_t*)(src + off),
                    (__attribute__((address_space(3))) uint32_t*)(dst + (s << 2)),
                    16, 0, 0);
            }
        } else {
            for (int start = 0; start < chunks; start += 64) {
                int s = (start + 64 > chunks) ? max(chunks - 64, 0) : start;
                int idx = s + lane;
                if (idx >= chunks) idx = chunks - 1;
                const int fy  = (int)(((uint32_t)idx * M) >> 22);
                const int off = idx + fy * dW;
                __builtin_amdgcn_global_load_lds(
                    (const __attribute__((address_space(1))) uint32_t*)(src + off),
                    (__attribute__((address_space(3))) uint32_t*)(dst + s),
                    4, 0, 0);
            }
        }
    }

    // ---- descriptor staging: wave wv copies chunks [wv*98, wv*98+98) ----
    {
        const float* bsrc = (const float*)(ws_i + blobBase + k * BLOB_DW);
        const int i0 = wv * WCHUNK;
        __builtin_amdgcn_global_load_lds(
            (const __attribute__((address_space(1))) uint32_t*)(bsrc + ((i0 + lane) << 2)),
            (__attribute__((address_space(3))) uint32_t*)(s_desc + (i0 << 2)),
            16, 0, 0);
        __builtin_amdgcn_global_load_lds(
            (const __attribute__((address_space(1))) uint32_t*)(bsrc + ((i0 + WCHUNK - 64 + lane) << 2)),
            (__attribute__((address_space(3))) uint32_t*)(s_desc + ((i0 + WCHUNK - 64) << 2)),
            16, 0, 0);
    }

    asm volatile("s_waitcnt vmcnt(0)" ::: "memory");
    __syncthreads();

    // ---- gather-FMA tap loop: one bin per lane ----
    if (lane < NBINS) {
        const float*  t  = s_tile + wv * TILE_D;
        const float4* w4 = (const float4*)s_desc;
        const int4*   c4 = (const int4*)(s_desc + 4 * NSAMP);
        const int oy = lane / 7;
        const int ox = lane - oy * 7;
        const int sbase = oy * 28 + ox * 2;   // s = (2*oy)*14 + 2*ox
        float acc = 0.0f;
#pragma unroll
        for (int sy = 0; sy < 2; ++sy) {
#pragma unroll
            for (int sx = 0; sx < 2; ++sx) {
                const int s = sbase + sy * 14 + sx;
                const float4 w  = w4[s];
                const int4   cc = c4[s];
                acc += w.x * t[cc.x] + w.y * t[cc.y]
                     + w.z * t[cc.z] + w.w * t[cc.w];
            }
        }
        const int c = g * CPG + wv;
        out[((size_t)k * C_TOTAL + c) * NBINS + lane] = acc;
    }
}

extern "C" void kernel_launch(void* const* d_in, const int* in_sizes, int n_in,
                              void* d_out, int out_size, void* d_ws, size_t ws_size,
                              hipStream_t stream) {
    const float* f0   = (const float*)d_in[0];
    const float* f1   = (const float*)d_in[1];
    const float* f2   = (const float*)d_in[2];
    const float* f3   = (const float*)d_in[3];
    const float* rois = (const float*)d_in[4];
    float* out = (float*)d_out;
    int*   ws  = (int*)d_ws;

    const int K = in_sizes[4] / 5;
    const int blobBase = K * SD_STRIDE;   // dword offset of sample blobs

    roi_desc_kernel<<<K, 256, 0, stream>>>(rois, ws, blobBase);

    dim3 grid(NGROUPS, K, 1);
    roi_align_main<<<grid, 256, 0, stream>>>(f0, f1, f2, f3, ws, out, blobBase);
}